// Round 1
// baseline (1583.809 us; speedup 1.0000x reference)
//
#include <hip/hip_runtime.h>
#include <cstdint>
#include <cstddef>

#define N_NODES 50000
#define N_EDGES 800000
#define F_IN 128
#define H_HEADS 4
#define C1 64
#define C2 32
#define NEG_SLOPE 0.2f
#define EPS_GAT 1e-16f

// ---------------------------------------------------------------------------
// GEMM: X [Nr x K] row-major  @  W [K x M] row-major  ->  Hout [Nr x M]
// Tile: 16 rows x 64 cols per 256-thread block; x-tile staged in LDS;
// W streamed (L2-resident: W1 = 128 KB).
// ---------------------------------------------------------------------------
template<int K, int M>
__global__ __launch_bounds__(256) void gemm_kernel(const float* __restrict__ X,
                                                   const float* __restrict__ W,
                                                   float* __restrict__ Hout, int Nr) {
    __shared__ float xs[16 * K];
    const int row0 = blockIdx.x * 16;
    const int colBase = blockIdx.y * 64;

    // load the 16 x K x-tile (contiguous in memory)
    for (int i = threadIdx.x; i < 16 * K; i += 256) {
        int r = row0 + i / K;
        xs[i] = (r < Nr) ? X[(size_t)row0 * K + i] : 0.0f;
    }
    __syncthreads();

    const int m_local = threadIdx.x & 63;
    const int n_sub   = threadIdx.x >> 6;   // 0..3, handles rows n_sub + 4*r
    const int col = colBase + m_local;

    float acc[4] = {0.f, 0.f, 0.f, 0.f};
#pragma unroll 4
    for (int k = 0; k < K; ++k) {
        float wv = W[(size_t)k * M + col];   // coalesced across the wave
#pragma unroll
        for (int r = 0; r < 4; ++r)
            acc[r] += xs[(n_sub + 4 * r) * K + k] * wv;  // LDS broadcast (same addr/wave)
    }
#pragma unroll
    for (int r = 0; r < 4; ++r) {
        int row = row0 + n_sub + 4 * r;
        if (row < Nr) Hout[(size_t)row * M + col] = acc[r];
    }
}

// ---------------------------------------------------------------------------
// Per-node attention coefficients: a_s[n,h] = sum_c H[n,h,c] * att_s[h,c]
// One wave per node; shuffle reduction.
// ---------------------------------------------------------------------------
template<int Hn, int C>
__global__ __launch_bounds__(256) void att_kernel(const float* __restrict__ Hm,
                                                  const float* __restrict__ atts,
                                                  const float* __restrict__ attd,
                                                  float* __restrict__ as_,
                                                  float* __restrict__ ad_, int Nr) {
    int node = blockIdx.x * 4 + (threadIdx.x >> 6);
    int lane = threadIdx.x & 63;
    if (node >= Nr) return;   // wave-uniform branch
    const float* hrow = Hm + (size_t)node * (Hn * C);
#pragma unroll
    for (int h = 0; h < Hn; ++h) {
        float vs = 0.f, vd = 0.f;
        if (lane < C) {
            float hv = hrow[h * C + lane];
            vs = hv * atts[h * C + lane];
            vd = hv * attd[h * C + lane];
        }
#pragma unroll
        for (int off = 32; off > 0; off >>= 1) {
            vs += __shfl_down(vs, off, 64);
            vd += __shfl_down(vd, off, 64);
        }
        if (lane == 0) {
            as_[node * Hn + h] = vs;
            ad_[node * Hn + h] = vd;
        }
    }
}

// ---------------------------------------------------------------------------
// Per-edge logits: w = exp(leaky_relu(a_s[src]+a_d[dst])) (no max-shift; softmax
// is shift-invariant and logits are small), accumulate denominator per (dst,h).
// ---------------------------------------------------------------------------
__global__ __launch_bounds__(256) void edge_kernel(const int* __restrict__ src,
                                                   const int* __restrict__ dst,
                                                   const float* __restrict__ as_,
                                                   const float* __restrict__ ad_,
                                                   float* __restrict__ ew,
                                                   float* __restrict__ denom, int Ecnt) {
    int e = blockIdx.x * 256 + threadIdx.x;
    if (e >= Ecnt) return;
    int s = src[e], d = dst[e];
#pragma unroll
    for (int h = 0; h < H_HEADS; ++h) {
        float v = as_[s * H_HEADS + h] + ad_[d * H_HEADS + h];
        v = (v > 0.f) ? v : NEG_SLOPE * v;
        float w = __expf(v);
        ew[e * H_HEADS + h] = w;
        atomicAdd(&denom[d * H_HEADS + h], w);
    }
}

// ---------------------------------------------------------------------------
// Aggregation: agg[dst,h,c] += alpha[e,h] * H[src,h,c].  One wave per edge;
// lane j covers feature indices j, j+64, ... (coalesced gather + atomic scatter).
// ---------------------------------------------------------------------------
template<int Hn, int C>
__global__ __launch_bounds__(256) void agg_kernel(const int* __restrict__ src,
                                                  const int* __restrict__ dst,
                                                  const float* __restrict__ ew,
                                                  const float* __restrict__ denom,
                                                  const float* __restrict__ Hm,
                                                  float* __restrict__ agg, int Ecnt) {
    constexpr int HC = Hn * C;
    constexpr int PER = HC / 64;
    int e = blockIdx.x * 4 + (threadIdx.x >> 6);
    int lane = threadIdx.x & 63;
    if (e >= Ecnt) return;   // wave-uniform
    int s = src[e], d = dst[e];

    float aval = 0.f;
    if (lane < Hn) aval = ew[e * Hn + lane] / (denom[d * Hn + lane] + EPS_GAT);

    const float* hs = Hm + (size_t)s * HC;
    float* ag = agg + (size_t)d * HC;
#pragma unroll
    for (int k = 0; k < PER; ++k) {
        int j = lane + 64 * k;
        int h = j / C;
        float alpha = __shfl(aval, h, 64);
        atomicAdd(&ag[j], alpha * hs[j]);
    }
}

// ---------------------------------------------------------------------------
// Head-mean + bias (+ optional ReLU): out[n,c] = act(mean_h agg[n,h,c] + b[c])
// ---------------------------------------------------------------------------
template<int Hn, int C, bool RELU>
__global__ __launch_bounds__(256) void mean_bias_kernel(const float* __restrict__ agg,
                                                        const float* __restrict__ bias,
                                                        float* __restrict__ out, int Nr) {
    int idx = blockIdx.x * 256 + threadIdx.x;
    if (idx >= Nr * C) return;
    int n = idx / C, c = idx % C;
    const float* a = agg + (size_t)n * Hn * C;
    float v = 0.f;
#pragma unroll
    for (int h = 0; h < Hn; ++h) v += a[h * C + c];
    v = v * (1.0f / Hn) + bias[c];
    if (RELU) v = fmaxf(v, 0.f);
    out[idx] = v;
}

// ---------------------------------------------------------------------------
extern "C" void kernel_launch(void* const* d_in, const int* in_sizes, int n_in,
                              void* d_out, int out_size, void* d_ws, size_t ws_size,
                              hipStream_t stream) {
    const float* x    = (const float*)d_in[0];
    const int*   ei   = (const int*)d_in[1];
    const float* W1   = (const float*)d_in[2];
    const float* as1w = (const float*)d_in[3];
    const float* ad1w = (const float*)d_in[4];
    const float* b1   = (const float*)d_in[5];
    const float* W2   = (const float*)d_in[6];
    const float* as2w = (const float*)d_in[7];
    const float* ad2w = (const float*)d_in[8];
    const float* b2   = (const float*)d_in[9];
    float* out = (float*)d_out;

    const int* src = ei;             // edge_index[0]
    const int* dst = ei + N_EDGES;   // edge_index[1]

    char* ws = (char*)d_ws;
    size_t off = 0;
    auto alloc = [&](size_t bytes) -> void* {
        void* p = ws + off;
        off = (off + bytes + 255) & ~(size_t)255;
        return p;
    };
    float* h1    = (float*)alloc((size_t)N_NODES * H_HEADS * C1 * 4);  // 51.2 MB
    float* agg1  = (float*)alloc((size_t)N_NODES * H_HEADS * C1 * 4);  // 51.2 MB
    float* out1  = (float*)alloc((size_t)N_NODES * C1 * 4);            // 12.8 MB
    float* ew    = (float*)alloc((size_t)N_EDGES * H_HEADS * 4);       // 12.8 MB
    float* as_   = (float*)alloc((size_t)N_NODES * H_HEADS * 4);
    float* ad_   = (float*)alloc((size_t)N_NODES * H_HEADS * 4);
    float* denom = (float*)alloc((size_t)N_NODES * H_HEADS * 4);
    // aliases (lifetimes are disjoint):
    float* agg2 = h1;    // h1 dead after layer-1 aggregation
    float* h2   = agg1;  // agg1 dead after layer-1 head-mean

    // ---- layer 1 ----
    hipMemsetAsync(agg1, 0, (size_t)N_NODES * H_HEADS * C1 * 4, stream);
    hipMemsetAsync(denom, 0, (size_t)N_NODES * H_HEADS * 4, stream);

    dim3 g1((N_NODES + 15) / 16, (H_HEADS * C1) / 64);
    gemm_kernel<F_IN, H_HEADS * C1><<<g1, 256, 0, stream>>>(x, W1, h1, N_NODES);
    att_kernel<H_HEADS, C1><<<(N_NODES + 3) / 4, 256, 0, stream>>>(h1, as1w, ad1w, as_, ad_, N_NODES);
    edge_kernel<<<(N_EDGES + 255) / 256, 256, 0, stream>>>(src, dst, as_, ad_, ew, denom, N_EDGES);
    agg_kernel<H_HEADS, C1><<<(N_EDGES + 3) / 4, 256, 0, stream>>>(src, dst, ew, denom, h1, agg1, N_EDGES);
    mean_bias_kernel<H_HEADS, C1, true><<<(N_NODES * C1 + 255) / 256, 256, 0, stream>>>(agg1, b1, out1, N_NODES);

    // ---- layer 2 ----
    hipMemsetAsync(agg2, 0, (size_t)N_NODES * H_HEADS * C2 * 4, stream);
    hipMemsetAsync(denom, 0, (size_t)N_NODES * H_HEADS * 4, stream);

    dim3 g2((N_NODES + 15) / 16, (H_HEADS * C2) / 64);
    gemm_kernel<C1, H_HEADS * C2><<<g2, 256, 0, stream>>>(out1, W2, h2, N_NODES);
    att_kernel<H_HEADS, C2><<<(N_NODES + 3) / 4, 256, 0, stream>>>(h2, as2w, ad2w, as_, ad_, N_NODES);
    edge_kernel<<<(N_EDGES + 255) / 256, 256, 0, stream>>>(src, dst, as_, ad_, ew, denom, N_EDGES);
    agg_kernel<H_HEADS, C2><<<(N_EDGES + 3) / 4, 256, 0, stream>>>(src, dst, ew, denom, h2, agg2, N_EDGES);
    mean_bias_kernel<H_HEADS, C2, false><<<(N_NODES * C2 + 255) / 256, 256, 0, stream>>>(agg2, b2, out, N_NODES);
}

// Round 2
// 638.986 us; speedup vs baseline: 2.4786x; 2.4786x over previous
//
#include <hip/hip_runtime.h>
#include <cstdint>
#include <cstddef>

#define N_NODES 50000
#define N_EDGES 800000
#define F_IN 128
#define H_HEADS 4
#define C1 64
#define C2 32
#define NEG_SLOPE 0.2f
#define EPS_GAT 1e-16f

// ---------------------------------------------------------------------------
// GEMM: X [Nr x K] @ W [K x M] -> Hout [Nr x M], all row-major.
// 16 rows x 64 cols per 256-thread block; x-tile in LDS; W streamed (L2-hot).
// ---------------------------------------------------------------------------
template<int K, int M>
__global__ __launch_bounds__(256) void gemm_kernel(const float* __restrict__ X,
                                                   const float* __restrict__ W,
                                                   float* __restrict__ Hout, int Nr) {
    __shared__ float xs[16 * K];
    const int row0 = blockIdx.x * 16;
    const int colBase = blockIdx.y * 64;

    for (int i = threadIdx.x; i < 16 * K; i += 256) {
        int r = row0 + i / K;
        xs[i] = (r < Nr) ? X[(size_t)row0 * K + i] : 0.0f;
    }
    __syncthreads();

    const int m_local = threadIdx.x & 63;
    const int n_sub   = threadIdx.x >> 6;
    const int col = colBase + m_local;

    float acc[4] = {0.f, 0.f, 0.f, 0.f};
#pragma unroll 4
    for (int k = 0; k < K; ++k) {
        float wv = W[(size_t)k * M + col];
#pragma unroll
        for (int r = 0; r < 4; ++r)
            acc[r] += xs[(n_sub + 4 * r) * K + k] * wv;
    }
#pragma unroll
    for (int r = 0; r < 4; ++r) {
        int row = row0 + n_sub + 4 * r;
        if (row < Nr) Hout[(size_t)row * M + col] = acc[r];
    }
}

// ---------------------------------------------------------------------------
// Per-node attention coefficients: a_s[n,h] = sum_c H[n,h,c]*att_s[h,c].
// One wave per node; shuffle reduction.
// ---------------------------------------------------------------------------
template<int Hn, int C>
__global__ __launch_bounds__(256) void att_kernel(const float* __restrict__ Hm,
                                                  const float* __restrict__ atts,
                                                  const float* __restrict__ attd,
                                                  float* __restrict__ as_,
                                                  float* __restrict__ ad_, int Nr) {
    int node = blockIdx.x * 4 + (threadIdx.x >> 6);
    int lane = threadIdx.x & 63;
    if (node >= Nr) return;   // wave-uniform
    const float* hrow = Hm + (size_t)node * (Hn * C);
#pragma unroll
    for (int h = 0; h < Hn; ++h) {
        float vs = 0.f, vd = 0.f;
        if (lane < C) {
            float hv = hrow[h * C + lane];
            vs = hv * atts[h * C + lane];
            vd = hv * attd[h * C + lane];
        }
#pragma unroll
        for (int off = 32; off > 0; off >>= 1) {
            vs += __shfl_down(vs, off, 64);
            vd += __shfl_down(vd, off, 64);
        }
        if (lane == 0) {
            as_[node * Hn + h] = vs;
            ad_[node * Hn + h] = vd;
        }
    }
}

// ---------------------------------------------------------------------------
// CSR build (counting sort by dst): histogram -> scan -> scatter of src ids.
// ---------------------------------------------------------------------------
__global__ __launch_bounds__(256) void count_kernel(const int* __restrict__ dst,
                                                    int* __restrict__ deg, int Ecnt) {
    int e = blockIdx.x * 256 + threadIdx.x;
    if (e < Ecnt) atomicAdd(&deg[dst[e]], 1);
}

// Single-block exclusive scan over deg[0..n) -> row_off[0..n], cursor copy.
__global__ __launch_bounds__(1024) void scan_kernel(const int* __restrict__ deg,
                                                    int* __restrict__ row_off,
                                                    int* __restrict__ cursor, int n) {
    __shared__ int smem[1024];
    __shared__ int running;
    if (threadIdx.x == 0) running = 0;
    __syncthreads();
    for (int base = 0; base < n; base += 1024) {
        int i = base + (int)threadIdx.x;
        int v = (i < n) ? deg[i] : 0;
        smem[threadIdx.x] = v;
        __syncthreads();
        for (int off = 1; off < 1024; off <<= 1) {
            int t = (threadIdx.x >= (unsigned)off) ? smem[threadIdx.x - off] : 0;
            __syncthreads();
            smem[threadIdx.x] += t;
            __syncthreads();
        }
        int excl = smem[threadIdx.x] - v;
        if (i < n) {
            int ro = running + excl;
            row_off[i] = ro;
            cursor[i] = ro;
        }
        __syncthreads();
        if (threadIdx.x == 1023) running += smem[1023];
        __syncthreads();
    }
    if (threadIdx.x == 0) row_off[n] = running;
}

__global__ __launch_bounds__(256) void scatter_kernel(const int* __restrict__ src,
                                                      const int* __restrict__ dst,
                                                      int* __restrict__ cursor,
                                                      int* __restrict__ ssrc, int Ecnt) {
    int e = blockIdx.x * 256 + threadIdx.x;
    if (e >= Ecnt) return;
    int p = atomicAdd(&cursor[dst[e]], 1);
    ssrc[p] = src[e];
}

// ---------------------------------------------------------------------------
// Fused GAT aggregation: one wave per destination node.
//   out[d,c] = act( mean_h( (Σ_e w_e h[src_e,h,c]) / (Σ_e w_e + eps) ) + b[c] )
//   w_e = exp(leaky_relu(a_s[src]+a_d[dst]))  (softmax shift-invariance: no max)
// Lane L holds h-elements [L*PER, L*PER+PER) -> head = L>>4 for both layers.
// ---------------------------------------------------------------------------
template<int Hn, int C, bool RELU>
__global__ __launch_bounds__(256) void gat_agg_kernel(const int* __restrict__ row_off,
                                                      const int* __restrict__ ssrc,
                                                      const float* __restrict__ as_,
                                                      const float* __restrict__ ad_,
                                                      const float* __restrict__ Hm,
                                                      const float* __restrict__ bias,
                                                      float* __restrict__ out, int Nr) {
    constexpr int HC = Hn * C;       // 256 (L1) / 128 (L2)
    constexpr int PER = HC / 64;     // 4 / 2
    int node = blockIdx.x * 4 + (threadIdx.x >> 6);
    int lane = threadIdx.x & 63;
    if (node >= Nr) return;          // wave-uniform
    const int h = lane >> 4;         // this lane's head
    const float ad_h = ad_[node * Hn + h];

    int begin = row_off[node], end = row_off[node + 1];
    float acc[PER];
#pragma unroll
    for (int t = 0; t < PER; ++t) acc[t] = 0.f;
    float wsum = 0.f;

    for (int i = begin; i < end; ++i) {
        int s = ssrc[i];                          // broadcast load
        float logit = as_[s * Hn + h] + ad_h;     // 4 addrs/wave, broadcast
        logit = (logit > 0.f) ? logit : NEG_SLOPE * logit;
        float w = __expf(logit);
        wsum += w;
        const float* hp = Hm + (size_t)s * HC + lane * PER;
        if (PER == 4) {
            float4 v = *(const float4*)hp;        // 1 KB/wave, one dwordx4/lane
            acc[0] += w * v.x; acc[1] += w * v.y;
            acc[2] += w * v.z; acc[3] += w * v.w;
        } else {
            float2 v = *(const float2*)hp;
            acc[0] += w * v.x; acc[1] += w * v.y;
        }
    }

    const float inv = 1.f / (wsum + EPS_GAT);     // zero-degree: 0/eps = 0 ✓
#pragma unroll
    for (int t = 0; t < PER; ++t) {
        float v = acc[t] * inv;
        v += __shfl_xor(v, 16, 64);               // sum the 4 head groups
        v += __shfl_xor(v, 32, 64);
        acc[t] = v * (1.0f / Hn);
    }
    if (lane < 16) {                               // lanes 0..15: features PER*L+t
        int c0 = lane * PER;
        if (PER == 4) {
            float4 o;
            o.x = acc[0] + bias[c0 + 0];
            o.y = acc[1] + bias[c0 + 1];
            o.z = acc[2] + bias[c0 + 2];
            o.w = acc[3] + bias[c0 + 3];
            if (RELU) {
                o.x = fmaxf(o.x, 0.f); o.y = fmaxf(o.y, 0.f);
                o.z = fmaxf(o.z, 0.f); o.w = fmaxf(o.w, 0.f);
            }
            *(float4*)(out + (size_t)node * C + c0) = o;
        } else {
            float2 o;
            o.x = acc[0] + bias[c0 + 0];
            o.y = acc[1] + bias[c0 + 1];
            if (RELU) { o.x = fmaxf(o.x, 0.f); o.y = fmaxf(o.y, 0.f); }
            *(float2*)(out + (size_t)node * C + c0) = o;
        }
    }
}

// ---------------------------------------------------------------------------
extern "C" void kernel_launch(void* const* d_in, const int* in_sizes, int n_in,
                              void* d_out, int out_size, void* d_ws, size_t ws_size,
                              hipStream_t stream) {
    const float* x    = (const float*)d_in[0];
    const int*   ei   = (const int*)d_in[1];
    const float* W1   = (const float*)d_in[2];
    const float* as1w = (const float*)d_in[3];
    const float* ad1w = (const float*)d_in[4];
    const float* b1   = (const float*)d_in[5];
    const float* W2   = (const float*)d_in[6];
    const float* as2w = (const float*)d_in[7];
    const float* ad2w = (const float*)d_in[8];
    const float* b2   = (const float*)d_in[9];
    float* out = (float*)d_out;

    const int* src = ei;             // edge_index[0]
    const int* dst = ei + N_EDGES;   // edge_index[1]

    char* ws = (char*)d_ws;
    size_t off = 0;
    auto alloc = [&](size_t bytes) -> void* {
        void* p = ws + off;
        off = (off + bytes + 255) & ~(size_t)255;
        return p;
    };
    float* h1      = (float*)alloc((size_t)N_NODES * H_HEADS * C1 * 4);  // 51.2 MB
    float* out1    = (float*)alloc((size_t)N_NODES * C1 * 4);            // 12.8 MB
    float* h2      = (float*)alloc((size_t)N_NODES * H_HEADS * C2 * 4);  // 25.6 MB
    float* as_     = (float*)alloc((size_t)N_NODES * H_HEADS * 4);
    float* ad_     = (float*)alloc((size_t)N_NODES * H_HEADS * 4);
    int*   deg     = (int*)alloc((size_t)(N_NODES) * 4);
    int*   row_off = (int*)alloc((size_t)(N_NODES + 1) * 4);
    int*   cursor  = (int*)alloc((size_t)(N_NODES) * 4);
    int*   ssrc    = (int*)alloc((size_t)N_EDGES * 4);                   // 3.2 MB

    // ---- CSR build (shared by both layers) ----
    hipMemsetAsync(deg, 0, (size_t)N_NODES * 4, stream);
    count_kernel<<<(N_EDGES + 255) / 256, 256, 0, stream>>>(dst, deg, N_EDGES);
    scan_kernel<<<1, 1024, 0, stream>>>(deg, row_off, cursor, N_NODES);
    scatter_kernel<<<(N_EDGES + 255) / 256, 256, 0, stream>>>(src, dst, cursor, ssrc, N_EDGES);

    // ---- layer 1 ----
    dim3 g1((N_NODES + 15) / 16, (H_HEADS * C1) / 64);
    gemm_kernel<F_IN, H_HEADS * C1><<<g1, 256, 0, stream>>>(x, W1, h1, N_NODES);
    att_kernel<H_HEADS, C1><<<(N_NODES + 3) / 4, 256, 0, stream>>>(h1, as1w, ad1w, as_, ad_, N_NODES);
    gat_agg_kernel<H_HEADS, C1, true><<<(N_NODES + 3) / 4, 256, 0, stream>>>(
        row_off, ssrc, as_, ad_, h1, b1, out1, N_NODES);

    // ---- layer 2 ----
    dim3 g2((N_NODES + 15) / 16, (H_HEADS * C2) / 64);
    gemm_kernel<C1, H_HEADS * C2><<<g2, 256, 0, stream>>>(out1, W2, h2, N_NODES);
    att_kernel<H_HEADS, C2><<<(N_NODES + 3) / 4, 256, 0, stream>>>(h2, as2w, ad2w, as_, ad_, N_NODES);
    gat_agg_kernel<H_HEADS, C2, false><<<(N_NODES + 3) / 4, 256, 0, stream>>>(
        row_off, ssrc, as_, ad_, h2, b2, out, N_NODES);
}

// Round 3
// 439.708 us; speedup vs baseline: 3.6020x; 1.4532x over previous
//
#include <hip/hip_runtime.h>
#include <cstdint>
#include <cstddef>

#define N_NODES 50000
#define N_EDGES 800000
#define F_IN 128
#define H_HEADS 4
#define C1 64
#define C2 32
#define NEG_SLOPE 0.2f
#define EPS_GAT 1e-16f

__device__ __forceinline__ unsigned short f2bf(float x) {   // RNE f32->bf16
    unsigned int u = __float_as_uint(x);
    u += 0x7fffu + ((u >> 16) & 1u);
    return (unsigned short)(u >> 16);
}
__device__ __forceinline__ float bf2f_lo(unsigned int u) { return __uint_as_float(u << 16); }
__device__ __forceinline__ float bf2f_hi(unsigned int u) { return __uint_as_float(u & 0xffff0000u); }
__device__ __forceinline__ float bf2f(unsigned short s) { return __uint_as_float(((unsigned int)s) << 16); }

// ---------------------------------------------------------------------------
// GEMM: X [Nr x K] f32 @ W [K x M] f32 -> Hout [Nr x M] bf16.
// 64x64 tile / 256 thr / 4x4 microtile; A transposed in LDS (pad 68) so both
// fragment reads are ds_read_b128; K chunked by BK (LDS 2x17 KB -> 4 blk/CU).
// ---------------------------------------------------------------------------
template<int K, int M, int BK>
__global__ __launch_bounds__(256) void gemm_bf16_kernel(const float* __restrict__ X,
                                                        const float* __restrict__ W,
                                                        unsigned short* __restrict__ Hout,
                                                        int Nr) {
    __shared__ float At[BK * 68];   // At[k][r], padded
    __shared__ float Bs[BK * 68];   // Bs[k][c], padded
    const int row0 = blockIdx.x * 64;
    const int col0 = blockIdx.y * 64;
    const int t = threadIdx.x;
    const int tx = t & 15, ty = t >> 4;

    float acc[4][4];
#pragma unroll
    for (int i = 0; i < 4; ++i)
#pragma unroll
        for (int j = 0; j < 4; ++j) acc[i][j] = 0.f;

    for (int k0 = 0; k0 < K; k0 += BK) {
        constexpr int KQ = BK / 4;          // float4s per A row-chunk
        // stage A (64 rows x BK), transposed into At
#pragma unroll
        for (int j = 0; j < (64 * KQ) / 256; ++j) {
            int flat = t + 256 * j;
            int r = flat / KQ, kq = flat % KQ;
            int rg = row0 + r;
            float4 v = make_float4(0.f, 0.f, 0.f, 0.f);
            if (rg < Nr) v = *(const float4*)&X[(size_t)rg * K + k0 + 4 * kq];
            At[(4 * kq + 0) * 68 + r] = v.x;
            At[(4 * kq + 1) * 68 + r] = v.y;
            At[(4 * kq + 2) * 68 + r] = v.z;
            At[(4 * kq + 3) * 68 + r] = v.w;
        }
        // stage B (BK x 64) direct
#pragma unroll
        for (int j = 0; j < (BK * 16) / 256; ++j) {
            int flat = t + 256 * j;
            int k = flat / 16, cq = flat % 16;
            float4 v = *(const float4*)&W[(size_t)(k0 + k) * M + col0 + 4 * cq];
            *(float4*)&Bs[k * 68 + 4 * cq] = v;
        }
        __syncthreads();
#pragma unroll 8
        for (int k = 0; k < BK; ++k) {
            float4 a4 = *(const float4*)&At[k * 68 + 4 * ty];
            float4 b4 = *(const float4*)&Bs[k * 68 + 4 * tx];
            acc[0][0] += a4.x * b4.x; acc[0][1] += a4.x * b4.y; acc[0][2] += a4.x * b4.z; acc[0][3] += a4.x * b4.w;
            acc[1][0] += a4.y * b4.x; acc[1][1] += a4.y * b4.y; acc[1][2] += a4.y * b4.z; acc[1][3] += a4.y * b4.w;
            acc[2][0] += a4.z * b4.x; acc[2][1] += a4.z * b4.y; acc[2][2] += a4.z * b4.z; acc[2][3] += a4.z * b4.w;
            acc[3][0] += a4.w * b4.x; acc[3][1] += a4.w * b4.y; acc[3][2] += a4.w * b4.z; acc[3][3] += a4.w * b4.w;
        }
        __syncthreads();
    }
#pragma unroll
    for (int rr = 0; rr < 4; ++rr) {
        int row = row0 + 4 * ty + rr;
        if (row < Nr) {
            unsigned int p0 = (unsigned int)f2bf(acc[rr][0]) | ((unsigned int)f2bf(acc[rr][1]) << 16);
            unsigned int p1 = (unsigned int)f2bf(acc[rr][2]) | ((unsigned int)f2bf(acc[rr][3]) << 16);
            *(uint2*)&Hout[(size_t)row * M + col0 + 4 * tx] = make_uint2(p0, p1);
        }
    }
}

// ---------------------------------------------------------------------------
// Per-node attention coefficients from bf16 h.
// ---------------------------------------------------------------------------
template<int Hn, int C>
__global__ __launch_bounds__(256) void att_kernel(const unsigned short* __restrict__ Hm,
                                                  const float* __restrict__ atts,
                                                  const float* __restrict__ attd,
                                                  float* __restrict__ as_,
                                                  float* __restrict__ ad_, int Nr) {
    int node = blockIdx.x * 4 + (threadIdx.x >> 6);
    int lane = threadIdx.x & 63;
    if (node >= Nr) return;   // wave-uniform
    const unsigned short* hrow = Hm + (size_t)node * (Hn * C);
#pragma unroll
    for (int h = 0; h < Hn; ++h) {
        float vs = 0.f, vd = 0.f;
        if (lane < C) {
            float hv = bf2f(hrow[h * C + lane]);
            vs = hv * atts[h * C + lane];
            vd = hv * attd[h * C + lane];
        }
#pragma unroll
        for (int off = 32; off > 0; off >>= 1) {
            vs += __shfl_down(vs, off, 64);
            vd += __shfl_down(vd, off, 64);
        }
        if (lane == 0) {
            as_[node * Hn + h] = vs;
            ad_[node * Hn + h] = vd;
        }
    }
}

// ---------------------------------------------------------------------------
// CSR build: histogram -> wave-scan -> scatter.
// ---------------------------------------------------------------------------
__global__ __launch_bounds__(256) void count_kernel(const int* __restrict__ dst,
                                                    int* __restrict__ deg, int Ecnt) {
    int e = blockIdx.x * 256 + threadIdx.x;
    if (e < Ecnt) atomicAdd(&deg[dst[e]], 1);
}

__global__ __launch_bounds__(1024) void scan_kernel(const int* __restrict__ deg,
                                                    int* __restrict__ row_off,
                                                    int* __restrict__ cursor, int n) {
    __shared__ int woff[16];
    __shared__ int running;
    const int t = threadIdx.x, lane = t & 63, wid = t >> 6;
    if (t == 0) running = 0;
    __syncthreads();
    for (int base = 0; base < n; base += 1024) {
        const int i = base + t;
        const int v = (i < n) ? deg[i] : 0;
        int x = v;                                   // inclusive wave scan
#pragma unroll
        for (int off = 1; off < 64; off <<= 1) {
            int y = __shfl_up(x, off, 64);
            if (lane >= off) x += y;
        }
        if (lane == 63) woff[wid] = x;
        __syncthreads();
        if (wid == 0) {                              // scan the 16 wave totals
            int tot = (lane < 16) ? woff[lane] : 0;
            int xt = tot;
#pragma unroll
            for (int off = 1; off < 16; off <<= 1) {
                int y = __shfl_up(xt, off, 64);
                if (lane >= off) xt += y;
            }
            if (lane < 16) woff[lane] = running + (xt - tot);
            if (lane == 15) running += xt;           // after woff reads (lockstep)
        }
        __syncthreads();
        if (i < n) {
            const int excl = woff[wid] + (x - v);
            row_off[i] = excl;
            cursor[i] = excl;
        }
        __syncthreads();
    }
    if (t == 0) row_off[n] = running;
}

__global__ __launch_bounds__(256) void scatter_kernel(const int* __restrict__ src,
                                                      const int* __restrict__ dst,
                                                      int* __restrict__ cursor,
                                                      int* __restrict__ ssrc, int Ecnt) {
    int e = blockIdx.x * 256 + threadIdx.x;
    if (e >= Ecnt) return;
    int p = atomicAdd(&cursor[dst[e]], 1);
    ssrc[p] = src[e];
}

// ---------------------------------------------------------------------------
// Fused GAT aggregation, bf16 h, 4 edges per wave (16 lanes each).
// Group g = lane/16 handles edge begin+4*it+g; in-group lane l covers
// elements [l*PER, (l+1)*PER) -> head = l/4 (PER = C/4).  ssrc prefetched.
// ---------------------------------------------------------------------------
template<int Hn, int C, bool RELU>
__global__ __launch_bounds__(256) void gat_agg_kernel(const int* __restrict__ row_off,
                                                      const int* __restrict__ ssrc,
                                                      const float* __restrict__ as_,
                                                      const float* __restrict__ ad_,
                                                      const unsigned short* __restrict__ Hm,
                                                      const float* __restrict__ bias,
                                                      float* __restrict__ out, int Nr) {
    constexpr int HC = Hn * C;
    constexpr int PER = HC / 16;     // 16 (L1) / 8 (L2) elems per lane
    constexpr int NV = PER / 8;      // uint4 loads per lane: 2 / 1
    int node = blockIdx.x * 4 + (threadIdx.x >> 6);
    int lane = threadIdx.x & 63;
    if (node >= Nr) return;          // wave-uniform
    const int g = lane >> 4;
    const int l = lane & 15;
    const int h = l >> 2;
    const float ad_h = ad_[node * Hn + h];

    const int begin = row_off[node], end = row_off[node + 1];
    float acc[PER];
#pragma unroll
    for (int t = 0; t < PER; ++t) acc[t] = 0.f;
    float wsum = 0.f;

    const int iters = (end - begin + 3) >> 2;    // wave-uniform
    int idx = begin + g;
    int s = 0;
    if (iters > 0) s = ssrc[(idx < end) ? idx : begin];
    for (int it = 0; it < iters; ++it) {
        const bool active = (idx < end);
        const int idx_n = idx + 4;
        int s_n = s;
        if (idx_n < end) s_n = ssrc[idx_n];      // prefetch next edge's src
        float logit = as_[s * Hn + h] + ad_h;
        logit = (logit > 0.f) ? logit : NEG_SLOPE * logit;
        float w = active ? __expf(logit) : 0.f;
        const uint4* hp = (const uint4*)(Hm + (size_t)s * HC + l * PER);
        uint4 u0 = hp[0];
        wsum += w;
        acc[0] += w * bf2f_lo(u0.x); acc[1] += w * bf2f_hi(u0.x);
        acc[2] += w * bf2f_lo(u0.y); acc[3] += w * bf2f_hi(u0.y);
        acc[4] += w * bf2f_lo(u0.z); acc[5] += w * bf2f_hi(u0.z);
        acc[6] += w * bf2f_lo(u0.w); acc[7] += w * bf2f_hi(u0.w);
        if constexpr (NV == 2) {
            uint4 u1 = hp[1];
            acc[8]  += w * bf2f_lo(u1.x); acc[9]  += w * bf2f_hi(u1.x);
            acc[10] += w * bf2f_lo(u1.y); acc[11] += w * bf2f_hi(u1.y);
            acc[12] += w * bf2f_lo(u1.z); acc[13] += w * bf2f_hi(u1.z);
            acc[14] += w * bf2f_lo(u1.w); acc[15] += w * bf2f_hi(u1.w);
        }
        s = s_n; idx = idx_n;
    }

    // sum the 4 edge-groups (same elements, disjoint edges)
#pragma unroll
    for (int t = 0; t < PER; ++t) {
        acc[t] += __shfl_xor(acc[t], 16, 64);
        acc[t] += __shfl_xor(acc[t], 32, 64);
    }
    wsum += __shfl_xor(wsum, 16, 64);
    wsum += __shfl_xor(wsum, 32, 64);
    const float inv = 1.f / (wsum + EPS_GAT);    // zero-degree: 0/eps = 0
    float val[PER];
#pragma unroll
    for (int t = 0; t < PER; ++t) {
        float v = acc[t] * inv;
        v += __shfl_xor(v, 4, 64);               // head mean (lanes l, l+4, l+8, l+12)
        v += __shfl_xor(v, 8, 64);
        val[t] = v * (1.0f / Hn);
    }
    if (lane < 4) {                              // lanes 0..3 cover c = lane*PER + t
        const int c0 = lane * PER;
#pragma unroll
        for (int t4 = 0; t4 < PER / 4; ++t4) {
            float4 o;
            o.x = val[4 * t4 + 0] + bias[c0 + 4 * t4 + 0];
            o.y = val[4 * t4 + 1] + bias[c0 + 4 * t4 + 1];
            o.z = val[4 * t4 + 2] + bias[c0 + 4 * t4 + 2];
            o.w = val[4 * t4 + 3] + bias[c0 + 4 * t4 + 3];
            if (RELU) {
                o.x = fmaxf(o.x, 0.f); o.y = fmaxf(o.y, 0.f);
                o.z = fmaxf(o.z, 0.f); o.w = fmaxf(o.w, 0.f);
            }
            *(float4*)&out[(size_t)node * C + c0 + 4 * t4] = o;
        }
    }
}

// ---------------------------------------------------------------------------
extern "C" void kernel_launch(void* const* d_in, const int* in_sizes, int n_in,
                              void* d_out, int out_size, void* d_ws, size_t ws_size,
                              hipStream_t stream) {
    const float* x    = (const float*)d_in[0];
    const int*   ei   = (const int*)d_in[1];
    const float* W1   = (const float*)d_in[2];
    const float* as1w = (const float*)d_in[3];
    const float* ad1w = (const float*)d_in[4];
    const float* b1   = (const float*)d_in[5];
    const float* W2   = (const float*)d_in[6];
    const float* as2w = (const float*)d_in[7];
    const float* ad2w = (const float*)d_in[8];
    const float* b2   = (const float*)d_in[9];
    float* out = (float*)d_out;

    const int* src = ei;             // edge_index[0]
    const int* dst = ei + N_EDGES;   // edge_index[1]

    char* ws = (char*)d_ws;
    size_t off = 0;
    auto alloc = [&](size_t bytes) -> void* {
        void* p = ws + off;
        off = (off + bytes + 255) & ~(size_t)255;
        return p;
    };
    unsigned short* h1 = (unsigned short*)alloc((size_t)N_NODES * H_HEADS * C1 * 2);  // 25.6 MB
    float* out1        = (float*)alloc((size_t)N_NODES * C1 * 4);                     // 12.8 MB
    unsigned short* h2 = (unsigned short*)alloc((size_t)N_NODES * H_HEADS * C2 * 2);  // 12.8 MB
    float* as_     = (float*)alloc((size_t)N_NODES * H_HEADS * 4);
    float* ad_     = (float*)alloc((size_t)N_NODES * H_HEADS * 4);
    int*   deg     = (int*)alloc((size_t)N_NODES * 4);
    int*   row_off = (int*)alloc((size_t)(N_NODES + 1) * 4);
    int*   cursor  = (int*)alloc((size_t)N_NODES * 4);
    int*   ssrc    = (int*)alloc((size_t)N_EDGES * 4);

    // ---- CSR build (shared by both layers) ----
    hipMemsetAsync(deg, 0, (size_t)N_NODES * 4, stream);
    count_kernel<<<(N_EDGES + 255) / 256, 256, 0, stream>>>(dst, deg, N_EDGES);
    scan_kernel<<<1, 1024, 0, stream>>>(deg, row_off, cursor, N_NODES);
    scatter_kernel<<<(N_EDGES + 255) / 256, 256, 0, stream>>>(src, dst, cursor, ssrc, N_EDGES);

    // ---- layer 1 ----
    gemm_bf16_kernel<F_IN, H_HEADS * C1, 64><<<dim3((N_NODES + 63) / 64, (H_HEADS * C1) / 64), 256, 0, stream>>>(
        x, W1, h1, N_NODES);
    att_kernel<H_HEADS, C1><<<(N_NODES + 3) / 4, 256, 0, stream>>>(h1, as1w, ad1w, as_, ad_, N_NODES);
    gat_agg_kernel<H_HEADS, C1, true><<<(N_NODES + 3) / 4, 256, 0, stream>>>(
        row_off, ssrc, as_, ad_, h1, b1, out1, N_NODES);

    // ---- layer 2 ----
    gemm_bf16_kernel<C1, H_HEADS * C2, 64><<<dim3((N_NODES + 63) / 64, (H_HEADS * C2) / 64), 256, 0, stream>>>(
        out1, W2, h2, N_NODES);
    att_kernel<H_HEADS, C2><<<(N_NODES + 3) / 4, 256, 0, stream>>>(h2, as2w, ad2w, as_, ad_, N_NODES);
    gat_agg_kernel<H_HEADS, C2, false><<<(N_NODES + 3) / 4, 256, 0, stream>>>(
        row_off, ssrc, as_, ad_, h2, b2, out, N_NODES);
}

// Round 4
// 336.707 us; speedup vs baseline: 4.7038x; 1.3059x over previous
//
#include <hip/hip_runtime.h>
#include <hip/hip_fp16.h>
#include <cstdint>
#include <cstddef>

#define N_NODES 50000
#define N_EDGES 800000
#define F_IN 128
#define H_HEADS 4
#define C1 64
#define C2 32
#define NEG_SLOPE 0.2f
#define EPS_GAT 1e-16f

typedef _Float16 half8 __attribute__((ext_vector_type(8)));
typedef float f32x4 __attribute__((ext_vector_type(4)));

// ---------------------------------------------------------------------------
// Fused GEMM + attention-dot kernel.  h = X @ W, h stored f16;
// as_/ad_[n,h] += sum_c h[n,h,c]*att{s,d}[h,c]  (from fp32 acc, atomicAdd).
// Block: 256 thr (4 waves), tile 64 rows x 64 cols, whole K staged in LDS.
// MFMA 16x16x32 f16; wave w covers rows 16w..16w+15, all 64 cols (4 frags).
// InT: float (layer 1, cast f32->f16 in staging) or _Float16 (layer 2).
// ---------------------------------------------------------------------------
template<int K, int M, int Hn, int C, typename InT>
__global__ __launch_bounds__(256) void gemm_att_kernel(
        const InT* __restrict__ X, const float* __restrict__ W,
        _Float16* __restrict__ Hout,
        const float* __restrict__ atts, const float* __restrict__ attd,
        float* __restrict__ as_, float* __restrict__ ad_, int Nr) {
    constexpr int LDK = K + 8;        // f16 stride; (K+8)*2 B is a 16B multiple
    constexpr int HPB = 64 / C;       // heads spanned by the 64-col tile (1 or 2)
    __shared__ _Float16 Ah[64 * LDK];
    __shared__ _Float16 Bt[64 * LDK];
    const int row0 = blockIdx.x * 64;
    const int col0 = blockIdx.y * 64;
    const int t = threadIdx.x;
    const int wv = t >> 6;
    const int lane = t & 63;
    const int quad = lane >> 4;
    const int n16 = lane & 15;

    // ---- stage A ----
    if constexpr (sizeof(InT) == 4) {           // f32 input: cast in flight
        constexpr int KQ = K / 4;
#pragma unroll
        for (int j = 0; j < (64 * KQ) / 256; ++j) {
            int flat = t + 256 * j;
            int r = flat / KQ, kq = flat % KQ;
            int rg = row0 + r;
            float4 v = make_float4(0.f, 0.f, 0.f, 0.f);
            if (rg < Nr) v = *(const float4*)&X[(size_t)rg * K + 4 * kq];
            _Float16* p = &Ah[r * LDK + 4 * kq];
            p[0] = (_Float16)v.x; p[1] = (_Float16)v.y;
            p[2] = (_Float16)v.z; p[3] = (_Float16)v.w;
        }
    } else {                                    // f16 input: straight copy
        constexpr int KQ = K / 8;
#pragma unroll
        for (int j = 0; j < (64 * KQ) / 256; ++j) {
            int flat = t + 256 * j;
            int r = flat / KQ, kq = flat % KQ;
            int rg = row0 + r;
            uint4 v = make_uint4(0u, 0u, 0u, 0u);
            if (rg < Nr) v = *(const uint4*)&X[(size_t)rg * K + 8 * kq];
            *(uint4*)&Ah[r * LDK + 8 * kq] = v;
        }
    }
    // ---- stage B transposed: Bt[c][k] = W[k][col0+c] (small, L2-hot) ----
#pragma unroll
    for (int j = 0; j < K / 4; ++j) {
        int c = t & 63;
        int k = (t >> 6) + 4 * j;
        Bt[c * LDK + k] = (_Float16)W[(size_t)k * M + col0 + c];
    }
    __syncthreads();

    f32x4 acc[4];
#pragma unroll
    for (int nf = 0; nf < 4; ++nf) acc[nf] = (f32x4){0.f, 0.f, 0.f, 0.f};
    const _Float16* Ap = &Ah[(16 * wv + n16) * LDK + 8 * quad];
#pragma unroll
    for (int ki = 0; ki < K / 32; ++ki) {
        half8 af = *(const half8*)(Ap + 32 * ki);
#pragma unroll
        for (int nf = 0; nf < 4; ++nf) {
            half8 bf = *(const half8*)&Bt[(16 * nf + n16) * LDK + 32 * ki + 8 * quad];
            acc[nf] = __builtin_amdgcn_mfma_f32_16x16x32_f16(af, bf, acc[nf], 0, 0, 0);
        }
    }

    // ---- attention partial dots (C/D layout: col=lane&15, row=quad*4+r) ----
    float dps[HPB][4], dpd[HPB][4];
#pragma unroll
    for (int u = 0; u < HPB; ++u)
#pragma unroll
        for (int r = 0; r < 4; ++r) { dps[u][r] = 0.f; dpd[u][r] = 0.f; }
#pragma unroll
    for (int nf = 0; nf < 4; ++nf) {
        int gc = col0 + 16 * nf + n16;
        float cs = atts[gc], cd = attd[gc];
#pragma unroll
        for (int r = 0; r < 4; ++r) {
            float av = acc[nf][r];
            dps[(16 * nf) / C][r] += av * cs;
            dpd[(16 * nf) / C][r] += av * cd;
        }
    }
#pragma unroll
    for (int u = 0; u < HPB; ++u)
#pragma unroll
        for (int r = 0; r < 4; ++r) {
            float s = dps[u][r], d = dpd[u][r];
#pragma unroll
            for (int off = 1; off < 16; off <<= 1) {
                s += __shfl_xor(s, off, 64);
                d += __shfl_xor(d, off, 64);
            }
            dps[u][r] = s; dpd[u][r] = d;
        }
    if (n16 == 0) {
        const int h0 = col0 / C;
#pragma unroll
        for (int r = 0; r < 4; ++r) {
            int row = row0 + 16 * wv + 4 * quad + r;
            if (row < Nr) {
#pragma unroll
                for (int u = 0; u < HPB; ++u) {
                    atomicAdd(&as_[row * Hn + h0 + u], dps[u][r]);
                    atomicAdd(&ad_[row * Hn + h0 + u], dpd[u][r]);
                }
            }
        }
    }

    // ---- store h tile: bounce via LDS (stride 72 f16) for dwordx4 stores ----
    __syncthreads();                  // all frag reads of Ah done
    _Float16* Ht = Ah;
#pragma unroll
    for (int nf = 0; nf < 4; ++nf)
#pragma unroll
        for (int r = 0; r < 4; ++r)
            Ht[(16 * wv + 4 * quad + r) * 72 + 16 * nf + n16] = (_Float16)acc[nf][r];
    __syncthreads();
#pragma unroll
    for (int j = 0; j < 2; ++j) {
        int chunk = t + 256 * j;      // 64 rows x 8 chunks of 8 f16
        int r = chunk >> 3, cc = chunk & 7;
        int row = row0 + r;
        if (row < Nr) {
            uint4 v = *(const uint4*)&Ht[r * 72 + 8 * cc];
            *(uint4*)&Hout[(size_t)row * M + col0 + 8 * cc] = v;
        }
    }
}

// ---------------------------------------------------------------------------
// CSR build: histogram -> 3-stage multi-block scan -> scatter.
// ---------------------------------------------------------------------------
__global__ __launch_bounds__(256) void count_kernel(const int* __restrict__ dst,
                                                    int* __restrict__ deg, int Ecnt) {
    int e = blockIdx.x * 256 + threadIdx.x;
    if (e < Ecnt) atomicAdd(&deg[dst[e]], 1);
}

__global__ __launch_bounds__(256) void scan_partial(const int* __restrict__ deg,
                                                    int* __restrict__ bsum, int n) {
    int i = blockIdx.x * 256 + threadIdx.x;
    int v = (i < n) ? deg[i] : 0;
    int lane = threadIdx.x & 63, wv = threadIdx.x >> 6;
#pragma unroll
    for (int off = 32; off > 0; off >>= 1) v += __shfl_down(v, off, 64);
    __shared__ int wt[4];
    if (lane == 0) wt[wv] = v;
    __syncthreads();
    if (threadIdx.x == 0) bsum[blockIdx.x] = wt[0] + wt[1] + wt[2] + wt[3];
}

__global__ __launch_bounds__(256) void scan_base(int* __restrict__ bsum, int nb,
                                                 int* __restrict__ total_out) {
    int t = threadIdx.x, lane = t & 63, wv = t >> 6;
    int v = (t < nb) ? bsum[t] : 0;
    int x = v;
#pragma unroll
    for (int off = 1; off < 64; off <<= 1) {
        int y = __shfl_up(x, off, 64);
        if (lane >= off) x += y;
    }
    __shared__ int wt[4];
    if (lane == 63) wt[wv] = x;
    __syncthreads();
    int base = 0;
    for (int k = 0; k < wv; ++k) base += wt[k];
    if (t < nb) bsum[t] = base + x - v;      // exclusive prefix
    if (t == 255) *total_out = base + x;     // grand total -> row_off[N]
}

__global__ __launch_bounds__(256) void scan_final(const int* __restrict__ deg,
                                                  const int* __restrict__ bsum,
                                                  int* __restrict__ row_off,
                                                  int* __restrict__ cursor, int n) {
    int i = blockIdx.x * 256 + threadIdx.x;
    int t = threadIdx.x, lane = t & 63, wv = t >> 6;
    int v = (i < n) ? deg[i] : 0;
    int x = v;
#pragma unroll
    for (int off = 1; off < 64; off <<= 1) {
        int y = __shfl_up(x, off, 64);
        if (lane >= off) x += y;
    }
    __shared__ int wt[4];
    if (lane == 63) wt[wv] = x;
    __syncthreads();
    int base = bsum[blockIdx.x];
    for (int k = 0; k < wv; ++k) base += wt[k];
    int ro = base + x - v;
    if (i < n) { row_off[i] = ro; cursor[i] = ro; }
}

__global__ __launch_bounds__(256) void scatter_kernel(const int* __restrict__ src,
                                                      const int* __restrict__ dst,
                                                      int* __restrict__ cursor,
                                                      int* __restrict__ ssrc, int Ecnt) {
    int e = blockIdx.x * 256 + threadIdx.x;
    if (e >= Ecnt) return;
    int p = atomicAdd(&cursor[dst[e]], 1);
    ssrc[p] = src[e];
}

// ---------------------------------------------------------------------------
// Fused GAT aggregation, f16 h, 4 edges/wave (16 lanes each), software-
// pipelined: ssrc 2 ahead, (a_s, h-vector) 1 iteration ahead in registers.
// In-group lane l covers h-row elements [l*PER,(l+1)*PER), head = l>>2.
// ---------------------------------------------------------------------------
template<int Hn, int C, bool RELU, bool OUT_F16>
__global__ __launch_bounds__(256) void gat_agg_kernel(
        const int* __restrict__ row_off, const int* __restrict__ ssrc,
        const float* __restrict__ as_, const float* __restrict__ ad_,
        const _Float16* __restrict__ Hm, const float* __restrict__ bias,
        void* __restrict__ outv, int Nr) {
    constexpr int HC = Hn * C;
    constexpr int PER = HC / 16;     // f16 per lane: 16 (L1) / 8 (L2)
    constexpr int NV = PER / 8;      // uint4 per lane: 2 / 1
    int node = blockIdx.x * 4 + (threadIdx.x >> 6);
    int lane = threadIdx.x & 63;
    if (node >= Nr) return;          // wave-uniform
    const int g = lane >> 4;
    const int l = lane & 15;
    const int h = l >> 2;
    const float ad_h = ad_[node * Hn + h];

    const int begin = row_off[node], end = row_off[node + 1];
    const int iters = (end - begin + 3) >> 2;   // wave-uniform

    float acc[PER];
#pragma unroll
    for (int t = 0; t < PER; ++t) acc[t] = 0.f;
    float wsum = 0.f;

    int idx = begin + g;
    int s_cur = (idx < end) ? ssrc[idx] : -1;
    int s_nx = (idx + 4 < end) ? ssrc[idx + 4] : -1;
    float a_cur = 0.f;
    uint4 u_cur[NV] = {};
    if (s_cur >= 0) {
        a_cur = as_[s_cur * Hn + h];
        const uint4* hp = (const uint4*)(Hm + (size_t)s_cur * HC + l * PER);
        u_cur[0] = hp[0];
        if constexpr (NV == 2) u_cur[1] = hp[1];
    }

    for (int it = 0; it < iters; ++it) {
        const int s_pf = s_nx;
        s_nx = (idx + 8 < end) ? ssrc[idx + 8] : -1;
        float a_nx = 0.f;
        uint4 u_nx[NV] = {};
        if (s_pf >= 0) {
            a_nx = as_[s_pf * Hn + h];
            const uint4* hp = (const uint4*)(Hm + (size_t)s_pf * HC + l * PER);
            u_nx[0] = hp[0];
            if constexpr (NV == 2) u_nx[1] = hp[1];
        }
        // compute current (inactive tail: w=0, u_cur zeroed -> no-op)
        float logit = a_cur + ad_h;
        logit = (logit > 0.f) ? logit : NEG_SLOPE * logit;
        float w = (s_cur >= 0) ? __expf(logit) : 0.f;
        wsum += w;
#pragma unroll
        for (int v = 0; v < NV; ++v) {
            float2 f;
            f = __half22float2(*(const __half2*)&u_cur[v].x);
            acc[8 * v + 0] += w * f.x; acc[8 * v + 1] += w * f.y;
            f = __half22float2(*(const __half2*)&u_cur[v].y);
            acc[8 * v + 2] += w * f.x; acc[8 * v + 3] += w * f.y;
            f = __half22float2(*(const __half2*)&u_cur[v].z);
            acc[8 * v + 4] += w * f.x; acc[8 * v + 5] += w * f.y;
            f = __half22float2(*(const __half2*)&u_cur[v].w);
            acc[8 * v + 6] += w * f.x; acc[8 * v + 7] += w * f.y;
        }
        s_cur = s_pf; a_cur = a_nx;
#pragma unroll
        for (int v = 0; v < NV; ++v) u_cur[v] = u_nx[v];
        idx += 4;
    }

#pragma unroll
    for (int t = 0; t < PER; ++t) {
        acc[t] += __shfl_xor(acc[t], 16, 64);
        acc[t] += __shfl_xor(acc[t], 32, 64);
    }
    wsum += __shfl_xor(wsum, 16, 64);
    wsum += __shfl_xor(wsum, 32, 64);
    const float inv = 1.f / (wsum + EPS_GAT);    // zero-degree: 0/eps = 0
    float val[PER];
#pragma unroll
    for (int t = 0; t < PER; ++t) {
        float v = acc[t] * inv;
        v += __shfl_xor(v, 4, 64);               // head mean
        v += __shfl_xor(v, 8, 64);
        val[t] = v * (1.0f / Hn);
    }
    if (lane < 4) {
        const int c0 = lane * PER;
#pragma unroll
        for (int t = 0; t < PER; ++t) {
            float v = val[t] + bias[c0 + t];
            if (RELU) v = fmaxf(v, 0.f);
            val[t] = v;
        }
        if constexpr (OUT_F16) {
            _Float16* o = (_Float16*)outv;
            _Float16 tmp[PER];
#pragma unroll
            for (int t = 0; t < PER; ++t) tmp[t] = (_Float16)val[t];
            uint4* d4 = (uint4*)&o[(size_t)node * C + c0];
            d4[0] = *(const uint4*)&tmp[0];
            if constexpr (NV == 2) d4[1] = *(const uint4*)&tmp[8];
        } else {
            float* o = (float*)outv;
#pragma unroll
            for (int t4 = 0; t4 < PER / 4; ++t4)
                *(float4*)&o[(size_t)node * C + c0 + 4 * t4] =
                    make_float4(val[4 * t4 + 0], val[4 * t4 + 1],
                                val[4 * t4 + 2], val[4 * t4 + 3]);
        }
    }
}

// ---------------------------------------------------------------------------
extern "C" void kernel_launch(void* const* d_in, const int* in_sizes, int n_in,
                              void* d_out, int out_size, void* d_ws, size_t ws_size,
                              hipStream_t stream) {
    const float* x    = (const float*)d_in[0];
    const int*   ei   = (const int*)d_in[1];
    const float* W1   = (const float*)d_in[2];
    const float* as1w = (const float*)d_in[3];
    const float* ad1w = (const float*)d_in[4];
    const float* b1   = (const float*)d_in[5];
    const float* W2   = (const float*)d_in[6];
    const float* as2w = (const float*)d_in[7];
    const float* ad2w = (const float*)d_in[8];
    const float* b2   = (const float*)d_in[9];
    float* out = (float*)d_out;

    const int* src = ei;             // edge_index[0]
    const int* dst = ei + N_EDGES;   // edge_index[1]

    char* ws = (char*)d_ws;
    size_t off = 0;
    auto alloc = [&](size_t bytes) -> void* {
        void* p = ws + off;
        off = (off + bytes + 255) & ~(size_t)255;
        return p;
    };
    const int NB = (N_NODES + 255) / 256;   // 196 scan blocks
    // deg | as_ | ad_ contiguous so one memset zeros all three
    int*   deg     = (int*)alloc((size_t)N_NODES * 4);
    float* as_     = (float*)alloc((size_t)N_NODES * H_HEADS * 4);
    float* ad_     = (float*)alloc((size_t)N_NODES * H_HEADS * 4);
    _Float16* h1   = (_Float16*)alloc((size_t)N_NODES * H_HEADS * C1 * 2);  // 25.6 MB
    _Float16* out1 = (_Float16*)alloc((size_t)N_NODES * C1 * 2);            // 6.4 MB
    _Float16* h2   = (_Float16*)alloc((size_t)N_NODES * H_HEADS * C2 * 2);  // 12.8 MB
    int*   row_off = (int*)alloc((size_t)(N_NODES + 1) * 4);
    int*   cursor  = (int*)alloc((size_t)N_NODES * 4);
    int*   ssrc    = (int*)alloc((size_t)N_EDGES * 4);
    int*   bsum    = (int*)alloc((size_t)NB * 4);

    const size_t zero_span1 = (char*)(ad_ + (size_t)N_NODES * H_HEADS) - (char*)deg;
    const size_t zero_span2 = (char*)(ad_ + (size_t)N_NODES * H_HEADS) - (char*)as_;

    // ---- CSR build ----
    hipMemsetAsync(deg, 0, zero_span1, stream);   // deg + as_ + ad_
    count_kernel<<<(N_EDGES + 255) / 256, 256, 0, stream>>>(dst, deg, N_EDGES);
    scan_partial<<<NB, 256, 0, stream>>>(deg, bsum, N_NODES);
    scan_base<<<1, 256, 0, stream>>>(bsum, NB, &row_off[N_NODES]);
    scan_final<<<NB, 256, 0, stream>>>(deg, bsum, row_off, cursor, N_NODES);
    scatter_kernel<<<(N_EDGES + 255) / 256, 256, 0, stream>>>(src, dst, cursor, ssrc, N_EDGES);

    // ---- layer 1 ----
    gemm_att_kernel<F_IN, H_HEADS * C1, H_HEADS, C1, float>
        <<<dim3((N_NODES + 63) / 64, (H_HEADS * C1) / 64), 256, 0, stream>>>(
            x, W1, h1, as1w, ad1w, as_, ad_, N_NODES);
    gat_agg_kernel<H_HEADS, C1, true, true><<<(N_NODES + 3) / 4, 256, 0, stream>>>(
        row_off, ssrc, as_, ad_, h1, b1, (void*)out1, N_NODES);

    // ---- layer 2 ----
    hipMemsetAsync(as_, 0, zero_span2, stream);   // re-zero as_ + ad_
    gemm_att_kernel<C1, H_HEADS * C2, H_HEADS, C2, _Float16>
        <<<dim3((N_NODES + 63) / 64, (H_HEADS * C2) / 64), 256, 0, stream>>>(
            out1, W2, h2, as2w, ad2w, as_, ad_, N_NODES);
    gat_agg_kernel<H_HEADS, C2, false, false><<<(N_NODES + 3) / 4, 256, 0, stream>>>(
        row_off, ssrc, as_, ad_, h2, b2, (void*)out, N_NODES);
}